// Round 1
// 389.405 us; speedup vs baseline: 1.2193x; 1.2193x over previous
//
#include <hip/hip_runtime.h>
#include <cstdint>
#include <cstddef>

#define T_TOKENS 8192
#define K_DIM 4096
#define N_DIM 4096
#define K_TILES 32  // K_DIM / 128

using i32x4 = __attribute__((ext_vector_type(4))) int;

// ---------------------------------------------------------------------------
// Kernel 0: pack harness-delivered int32 weight (one int8 per int32) into
// dense int8 [N][K].
// ---------------------------------------------------------------------------
__global__ __launch_bounds__(256) void pack_weight(const int* __restrict__ win,
                                                   int8_t* __restrict__ wout) {
    const int idx = blockIdx.x * 256 + threadIdx.x;  // one dword (4 int8) out
    const i32x4 v = reinterpret_cast<const i32x4*>(win)[idx];
    uint32_t pk = (uint32_t)(v.x & 255) | ((uint32_t)(v.y & 255) << 8) |
                  ((uint32_t)(v.z & 255) << 16) | ((uint32_t)(v.w & 255) << 24);
    reinterpret_cast<int*>(wout)[idx] = (int)pk;
}

// ---------------------------------------------------------------------------
// Kernel 1: per-token dynamic quantization (one 256-thread block per row).
// ---------------------------------------------------------------------------
__global__ __launch_bounds__(256) void quant_rows(const float* __restrict__ x,
                                                  int8_t* __restrict__ qx,
                                                  float* __restrict__ xscale) {
    const int t = blockIdx.x;
    const int tid = threadIdx.x;
    const float4* row = reinterpret_cast<const float4*>(x + (size_t)t * K_DIM);

    float4 v[4];
    float amax = 0.0f;
#pragma unroll
    for (int i = 0; i < 4; ++i) {
        v[i] = row[i * 256 + tid];
        amax = fmaxf(amax, fabsf(v[i].x));
        amax = fmaxf(amax, fabsf(v[i].y));
        amax = fmaxf(amax, fabsf(v[i].z));
        amax = fmaxf(amax, fabsf(v[i].w));
    }
#pragma unroll
    for (int off = 32; off > 0; off >>= 1)
        amax = fmaxf(amax, __shfl_xor(amax, off));

    __shared__ float red[4];
    if ((tid & 63) == 0) red[tid >> 6] = amax;
    __syncthreads();
    amax = fmaxf(fmaxf(red[0], red[1]), fmaxf(red[2], red[3]));

    const float scale = fmaxf(amax, 1e-30f) * (1.0f / 127.0f);
    if (tid == 0) xscale[t] = scale;

    int* qrow = reinterpret_cast<int*>(qx + (size_t)t * K_DIM);
#pragma unroll
    for (int i = 0; i < 4; ++i) {
        int q0 = (int)fminf(fmaxf(rintf(v[i].x / scale), -127.0f), 127.0f);
        int q1 = (int)fminf(fmaxf(rintf(v[i].y / scale), -127.0f), 127.0f);
        int q2 = (int)fminf(fmaxf(rintf(v[i].z / scale), -127.0f), 127.0f);
        int q3 = (int)fminf(fmaxf(rintf(v[i].w / scale), -127.0f), 127.0f);
        uint32_t pk = (uint32_t)(q0 & 255) | ((uint32_t)(q1 & 255) << 8) |
                      ((uint32_t)(q2 & 255) << 16) | ((uint32_t)(q3 & 255) << 24);
        qrow[i * 256 + tid] = (int)pk;
    }
}

// ---------------------------------------------------------------------------
// Kernel 2: int8 GEMM, 256x256 tile, BK=128, 8 waves (2M x 4N), 8-phase-style
// schedule: global_load_lds (16B) staging, LDS double-buffer (128 KiB),
// counted vmcnt(6), XOR-swizzled LDS (conflict-free frag reads), setprio
// around MFMA clusters, XCD-aware block swizzle.
//
// LDS layout (bytes): [buf:2][op A/B:2][ksl:2][256 rows][64] = 131072.
// Slab (op,ksl) holds K-slice bytes [ksl*64, ksl*64+64) of all 256 rows,
// with per-row col swizzle  col_lds = col_g ^ (((row>>1)&3)<<4)  applied on
// the *global source* (linear LDS dest, rule: both-sides-or-neither).
//
// Fragment conventions (identical to the verified previous kernel):
//  A/B: 16 contiguous K bytes per lane: row = base + (lane&15), kbytes at
//  (lane>>4)*16.  C/D: col = lane&15, row = (lane>>4)*4 + reg.
// ---------------------------------------------------------------------------
__global__ __launch_bounds__(512, 2) void int8_gemm(const int8_t* __restrict__ qx,
                                                    const int8_t* __restrict__ w,
                                                    const float* __restrict__ xscale,
                                                    const float* __restrict__ wscale,
                                                    const float* __restrict__ bias,
                                                    float* __restrict__ out) {
    extern __shared__ int8_t lds[];  // 131072 bytes

    const int tid = threadIdx.x;
    const int lane = tid & 63;
    const int wave = tid >> 6;
    const int wr = wave >> 2;  // 0..1 : 128 token rows
    const int wn = wave & 3;   // 0..3 : 64 feature cols
    const int l16 = lane & 15;
    const int quad = lane >> 4;

    // XCD-aware swizzle: 512 blocks, 64 contiguous per XCD, M-major chunks
    // so each XCD's 4 A-panels (4 MB) fit its private L2.
    const int wg = ((blockIdx.x & 7) << 6) | ((int)blockIdx.x >> 3);
    const int tm = wg >> 4;  // 0..31
    const int tn = wg & 15;  // 0..15

    const int8_t* gA = qx + (size_t)tm * 256 * K_DIM;
    const int8_t* gB = w + (size_t)tn * 256 * K_DIM;

    // staging coords: thread covers row (tid>>2)+e*128, 16B chunk (tid&3)
    const int s_row = tid >> 2;
    const int scol = (((tid & 3) ^ ((tid >> 3) & 3)) << 4);  // pre-swizzled src col
    // fragment read col (lane-constant): quad*16 ^ (((l16>>1)&3)<<4)
    const int fcol = ((quad ^ ((l16 >> 1) & 3)) << 4);

    const int ldsA_rd = (wr * 128 + l16) * 64 + fcol;           // + mh*4096 + q*1024
    const int ldsB_rd = 32768 + (wn * 64 + l16) * 64 + fcol;    // + nj*1024

#define STAGE2(buf, op, ksl, k0)                                                        \
    {                                                                                   \
        const int8_t* g_ = ((op) ? gB : gA) +                                           \
                           ((size_t)s_row * K_DIM + (size_t)((k0) + (ksl) * 64 + scol));\
        int8_t* l_ = lds + (buf) * 65536 + (op) * 32768 + (ksl) * 16384 + tid * 16;     \
        __builtin_amdgcn_global_load_lds(                                               \
            (const __attribute__((address_space(1))) void*)g_,                          \
            (__attribute__((address_space(3))) void*)l_, 16, 0, 0);                     \
        __builtin_amdgcn_global_load_lds(                                               \
            (const __attribute__((address_space(1))) void*)(g_ + (size_t)128 * K_DIM),  \
            (__attribute__((address_space(3))) void*)(l_ + 8192), 16, 0, 0);            \
    }

    i32x4 acc[8][4] = {};
    i32x4 af[4], bf[4];

#define READ_B(buf, ksl)                                                     \
    {                                                                        \
        const int8_t* sB_ = lds + (buf) * 65536 + (ksl) * 16384 + ldsB_rd;   \
        _Pragma("unroll") for (int nj = 0; nj < 4; ++nj)                     \
            bf[nj] = *(const i32x4*)(sB_ + nj * 1024);                       \
    }
#define READ_A(buf, ksl, mh)                                                 \
    {                                                                        \
        const int8_t* sA_ =                                                  \
            lds + (buf) * 65536 + (ksl) * 16384 + (mh) * 4096 + ldsA_rd;     \
        _Pragma("unroll") for (int q = 0; q < 4; ++q)                        \
            af[q] = *(const i32x4*)(sA_ + q * 1024);                         \
    }
#define MFMA16(mh)                                                           \
    __builtin_amdgcn_s_setprio(1);                                           \
    _Pragma("unroll") for (int q = 0; q < 4; ++q) {                          \
        _Pragma("unroll") for (int nj = 0; nj < 4; ++nj)                     \
            acc[(mh) * 4 + q][nj] = __builtin_amdgcn_mfma_i32_16x16x64_i8(   \
                af[q], bf[nj], acc[(mh) * 4 + q][nj], 0, 0, 0);              \
    }                                                                        \
    __builtin_amdgcn_s_setprio(0);

    // prologue: stage tile 0 into buf 0, order A0 B0 A1 B1 (oldest first)
    STAGE2(0, 0, 0, 0)
    STAGE2(0, 1, 0, 0)
    STAGE2(0, 0, 1, 0)
    STAGE2(0, 1, 1, 0)

    // Steady state vmcnt ledger (units: gload ops/wave, each STAGE2 = 2):
    //  ph0: issue A0(t+1) -> 10 outstanding; vmcnt(6) drains A0(t),B0(t)
    //  ph2: issue A1(t+1) -> 10 outstanding; vmcnt(6) drains A1(t),B1(t)
    for (int t = 0; t < K_TILES - 1; ++t) {
        const int cur = t & 1;
        const int nxt = cur ^ 1;
        const int k1 = (t + 1) << 7;

        // phase 0: compute (ksl0, mh0) ; prefetch A-slab0(t+1)
        STAGE2(nxt, 0, 0, k1)
        asm volatile("s_waitcnt vmcnt(6)" ::: "memory");
        __builtin_amdgcn_s_barrier();
        READ_B(cur, 0)
        READ_A(cur, 0, 0)
        MFMA16(0)
        __builtin_amdgcn_s_barrier();

        // phase 1: (ksl0, mh1) ; prefetch B-slab0(t+1)
        STAGE2(nxt, 1, 0, k1)
        READ_A(cur, 0, 1)
        MFMA16(1)
        __builtin_amdgcn_s_barrier();

        // phase 2: (ksl1, mh0) ; prefetch A-slab1(t+1)
        STAGE2(nxt, 0, 1, k1)
        asm volatile("s_waitcnt vmcnt(6)" ::: "memory");
        __builtin_amdgcn_s_barrier();
        READ_B(cur, 1)
        READ_A(cur, 1, 0)
        MFMA16(0)
        __builtin_amdgcn_s_barrier();

        // phase 3: (ksl1, mh1) ; prefetch B-slab1(t+1)
        STAGE2(nxt, 1, 1, k1)
        READ_A(cur, 1, 1)
        MFMA16(1)
        __builtin_amdgcn_s_barrier();
    }

    // tail tile (t = K_TILES-1, buf = 1): no prefetch; drain counted 4 -> 0
    {
        asm volatile("s_waitcnt vmcnt(4)" ::: "memory");
        __builtin_amdgcn_s_barrier();
        READ_B(1, 0)
        READ_A(1, 0, 0)
        MFMA16(0)
        __builtin_amdgcn_s_barrier();
        READ_A(1, 0, 1)
        MFMA16(1)
        __builtin_amdgcn_s_barrier();
        asm volatile("s_waitcnt vmcnt(0)" ::: "memory");
        __builtin_amdgcn_s_barrier();
        READ_B(1, 1)
        READ_A(1, 1, 0)
        MFMA16(0)
        __builtin_amdgcn_s_barrier();
        READ_A(1, 1, 1)
        MFMA16(1)
    }

    // epilogue: dequant + bias.  C/D: col = l16, row = quad*4 + reg.
    const int row_base = tm * 256 + wr * 128 + quad * 4;
    const int col_base = tn * 256 + wn * 64 + l16;
    float wsv[4], bsv[4];
#pragma unroll
    for (int nj = 0; nj < 4; ++nj) {
        wsv[nj] = wscale[col_base + nj * 16];
        bsv[nj] = bias[col_base + nj * 16];
    }
#pragma unroll
    for (int mi = 0; mi < 8; ++mi) {
#pragma unroll
        for (int r = 0; r < 4; ++r) {
            const int trow = row_base + mi * 16 + r;
            const float xs = xscale[trow];
            float* orow = out + (size_t)trow * N_DIM + col_base;
#pragma unroll
            for (int nj = 0; nj < 4; ++nj)
                orow[nj * 16] = (float)acc[mi][nj][r] * (wsv[nj] * xs) + bsv[nj];
        }
    }
#undef STAGE2
#undef READ_B
#undef READ_A
#undef MFMA16
}

extern "C" void kernel_launch(void* const* d_in, const int* in_sizes, int n_in,
                              void* d_out, int out_size, void* d_ws, size_t ws_size,
                              hipStream_t stream) {
    const float* x = (const float*)d_in[0];
    const int* w_i32 = (const int*)d_in[1];
    const float* wscale = (const float*)d_in[2];
    const float* bias = (const float*)d_in[3];
    float* out = (float*)d_out;

    // workspace: qx (32 MB) | xscale (32 KB pad to 64 KB) | packed weight (16 MB)
    int8_t* qx = (int8_t*)d_ws;
    float* xscale = (float*)((char*)d_ws + (size_t)T_TOKENS * K_DIM);
    int8_t* wpk = (int8_t*)((char*)d_ws + (size_t)T_TOKENS * K_DIM + 65536);

    static bool attr_set = false;
    if (!attr_set) {
        (void)hipFuncSetAttribute(reinterpret_cast<const void*>(&int8_gemm),
                                  hipFuncAttributeMaxDynamicSharedMemorySize, 131072);
        attr_set = true;
    }

    pack_weight<<<(N_DIM * K_DIM / 4) / 256, 256, 0, stream>>>(w_i32, wpk);
    quant_rows<<<T_TOKENS, 256, 0, stream>>>(x, qx, xscale);
    int8_gemm<<<dim3(512), dim3(512), 131072, stream>>>(qx, wpk, xscale, wscale, bias, out);
}